// Round 8
// baseline (284.426 us; speedup 1.0000x reference)
//
#include <hip/hip_runtime.h>
#include <hip/hip_bf16.h>

#define S_DIM 128
#define N_PTS 384
#define CM    64
#define C_DIM 32
#define CZ    128
#define NC    (N_PTS*C_DIM)   // 12288
#define HSA   (NC*128)        // 1572864 B: byte stride between k-halves of A_ws/B_ws

typedef __attribute__((ext_vector_type(8)))  __bf16 bf16x8;
typedef __attribute__((ext_vector_type(16))) float  f32x16;
typedef unsigned short u16;
typedef unsigned int   u32;

__device__ __forceinline__ bf16x8 lds_frag(const void* base, int byteoff){
  union { uint4 u; bf16x8 v; } x;
  x.u = *(const uint4*)((const char*)base + byteoff);
  return x.v;
}
__device__ __forceinline__ u16 bf16bits(float f){
  union { float f; u32 u; } x; x.f = f;
  u32 r = (x.u + 0x7fff + ((x.u >> 16) & 1)) >> 16;   // RNE
  return (u16)r;
}

// ---------------- kernel 0: W [1024,128] (f32) -> Wt_perm [128 z][1024 mem-idx] (bf16) ------
// mem idx mi: e=mi&7, j=(mi>>3)&3, hi=(mi>>5)&1, Q=mi>>6 ; ks=Q*4+j ; pos=ks*16+hi*8+e
// pos -> original k: c = ((pos>>7)<<2)|(pos&3), d = (pos>>2)&31, k = c*32+d
__global__ __launch_bounds__(256) void k_wt(const float* __restrict__ w_out,
                                            __hip_bfloat16* __restrict__ wt){
  int o = blockIdx.x*256 + threadIdx.x;     // 131072 total
  int z = o >> 10, mi = o & 1023;
  int e = mi & 7, j = (mi >> 3) & 3, hi = (mi >> 5) & 1, Q = mi >> 6;
  int ks = Q*4 + j;
  int pos = ks*16 + hi*8 + e;
  int c = ((pos >> 7) << 2) | (pos & 3);
  int d = (pos >> 2) & 31;
  int k = c*32 + d;
  wt[o] = (__hip_bfloat16)w_out[k*CZ + z];
}

// ---------------- kernel 0b: norm[i][j] = sum_s mask[s,i]*mask[s,j] ----------------
__global__ __launch_bounds__(384) void k_norm(const float* __restrict__ mask,
                                              float* __restrict__ nrm_g){
  int i = blockIdx.x, j = threadIdx.x;
  float a = 0.f;
  #pragma unroll 8
  for (int s = 0; s < S_DIM; ++s)
    a += mask[s*N_PTS + i] * mask[s*N_PTS + j];
  nrm_g[i*N_PTS + j] = a;
}

// ---------------- kernel 1: LN + projections via MFMA ----------------
// Output layout (A_ws/B_ws): for global row m = n*32+c, k = s (0..127):
//   byte = (s>>6)*HSA + (m>>1)*256 + (((m&1)*128 + (s&63)*2) ^ (((m>>1)&15)<<4))
// (pre-swizzled interleaved-rowpair; k_fused stages it as a pure linear copy)
__global__ __launch_bounds__(512) void k_lnproj(
    const float* __restrict__ msa, const float* __restrict__ mask,
    const float* __restrict__ gamma, const float* __restrict__ beta,
    const float* __restrict__ wa, const float* __restrict__ wb,
    __hip_bfloat16* __restrict__ A_ws, __hip_bfloat16* __restrict__ B_ws){
  __shared__ union {
    u16   X[128*64];     // 16KB bf16 LN'd [s][m]
    float T[64*128];     // 32KB f32 [col][s]
  } sh;
  __shared__ float ln_mk[128];

  const int tid = threadIdx.x, w = tid >> 6, l = tid & 63;
  const int hi = l >> 5, ln = l & 31;
  const int n = blockIdx.x;

  if (tid < 128) ln_mk[tid] = mask[tid*N_PTS + n];

  const float g  = gamma[l];
  const float be = beta[l];

  #pragma unroll
  for (int t = 0; t < 16; ++t){
    int s = w*16 + t;
    float x = msa[((size_t)s*N_PTS + n)*CM + l];
    float sum = x;
    #pragma unroll
    for (int m = 1; m < 64; m <<= 1) sum += __shfl_xor(sum, m, 64);
    float mu = sum * (1.0f/64.0f);
    float dx = x - mu;
    float vs = dx*dx;
    #pragma unroll
    for (int m = 1; m < 64; m <<= 1) vs += __shfl_xor(vs, m, 64);
    float rstd = rsqrtf(vs*(1.0f/64.0f) + 1e-5f);
    float xn = dx*rstd*g + be;
    *(u16*)((char*)sh.X + s*128 + ((l*2) ^ ((s&7)<<4))) = bf16bits(xn);
  }
  __syncthreads();

  const int mb = w >> 1, mat = w & 1;
  const float* W = mat ? wb : wa;
  f32x16 pacc;
  #pragma unroll
  for (int r = 0; r < 16; ++r) pacc[r] = 0.f;
  #pragma unroll
  for (int ks = 0; ks < 4; ++ks){
    int srow = mb*32 + ln;
    bf16x8 aF = lds_frag(sh.X, srow*128 + (((ks*32 + hi*16)) ^ ((srow&7)<<4)));
    union { u16 s[8]; bf16x8 v; } bx;
    #pragma unroll
    for (int e = 0; e < 8; ++e){
      int m = ks*16 + hi*8 + e;
      bx.s[e] = bf16bits(W[m*C_DIM + ln]);
    }
    pacc = __builtin_amdgcn_mfma_f32_32x32x16_bf16(aF, bx.v, pacc, 0, 0, 0);
  }
  __syncthreads();

  const int col = mat*32 + ln;
  #pragma unroll
  for (int r = 0; r < 16; ++r){
    int rr = (r & 3) + ((r >> 2) << 3) + (hi << 2);
    int s = mb*32 + rr;
    *(float*)((char*)sh.T + col*512 + ((s*4) ^ ((col&7)<<4))) = pacc[r] * ln_mk[s];
  }
  __syncthreads();

  {
    int col2 = tid >> 3, sc = tid & 7;
    __hip_bfloat16* O = (col2 < 32) ? A_ws : B_ws;
    int m = n*C_DIM + (col2 & 31);
    u16 outv[16];
    #pragma unroll
    for (int q = 0; q < 4; ++q){
      union { uint4 u4; float f[4]; } rd;
      rd.u4 = *(const uint4*)((const char*)sh.T + col2*512 + ((sc*64 + q*16) ^ ((col2&7)<<4)));
      #pragma unroll
      for (int e = 0; e < 4; ++e) outv[q*4 + e] = bf16bits(rd.f[e]);
    }
    uint4 pk0, pk1;
    u32* pw = (u32*)&pk0;
    #pragma unroll
    for (int q = 0; q < 4; ++q) pw[q] = (u32)outv[2*q] | ((u32)outv[2*q+1] << 16);
    u32* pw1 = (u32*)&pk1;
    #pragma unroll
    for (int q = 0; q < 4; ++q) pw1[q] = (u32)outv[8 + 2*q] | ((u32)outv[8 + 2*q+1] << 16);
    // dest: pre-swizzled interleaved-rowpair layout
    size_t base = (size_t)(sc >> 2)*HSA + (size_t)(m >> 1)*256;
    int    swz  = ((m >> 1) & 15) << 4;
    int    c0   = (m & 1)*128 + (sc & 3)*32;
    *(uint4*)((char*)O + base + ((c0)      ^ swz)) = pk0;
    *(uint4*)((char*)O + base + ((c0 + 16) ^ swz)) = pk1;
  }
}

// ---------------- kernel 2: fused, 8x4 tile, 4 waves, 2 blocks/CU ----------------
// grid (48,96), 256 threads. Stage B: M=256, N=128, K=128 (two 64-halves).
// Stage C: M=32 pairs, N=128, K=1024; waves (kh = K-half, zh = z-half).
__global__ __launch_bounds__(256, 2) void k_fused(
    const __hip_bfloat16* __restrict__ A_ws, const __hip_bfloat16* __restrict__ B_ws,
    const __hip_bfloat16* __restrict__ Wt,  const float* __restrict__ b_out,
    const float* __restrict__ nrm_g, float* __restrict__ out){
  __shared__ union {
    struct { u16 Ah[16384]; u16 Bh[8192]; } s1;   // 32KB + 16KB half-slabs (pre-swizzled)
    char P[65536];                                // 32 pairs x 2048B pos layout
  } sh;
  __shared__ float nrm[32];

  const int tid = threadIdx.x;
  const int w = tid >> 6, l = tid & 63;
  const int hi = l >> 5, ln = l & 31;
  const int bi = blockIdx.x, bj = blockIdx.y;
  const int wr = w;                    // stage-B M-block (4 x 64 rows)

  char* shA = (char*)sh.s1.Ah;
  char* shB = (char*)sh.s1.Bh;
  char* shP = sh.P;

  const char* AsrcB = (const char*)A_ws + (size_t)bi*32768;   // rowpairs bi*128, 32KB/half
  const char* BsrcB = (const char*)B_ws + (size_t)bj*16384;   // rowpairs bj*64, 16KB/half

  // ---- P0: load h0 -> regs; nrm ----
  uint4 sa[8], sb[4];
  #pragma unroll
  for (int it = 0; it < 8; ++it) sa[it] = *(const uint4*)(AsrcB + (it*256 + tid)*16);
  #pragma unroll
  for (int it = 0; it < 4; ++it) sb[it] = *(const uint4*)(BsrcB + (it*256 + tid)*16);
  if (tid < 32) nrm[tid] = nrm_g[(bi*8 + (tid >> 2))*N_PTS + bj*4 + (tid & 3)];

  // ---- write h0 to LDS (linear; swizzle pre-applied in global) ----
  #pragma unroll
  for (int it = 0; it < 8; ++it) *(uint4*)(shA + (it*256 + tid)*16) = sa[it];
  #pragma unroll
  for (int it = 0; it < 4; ++it) *(uint4*)(shB + (it*256 + tid)*16) = sb[it];

  // ---- T14: issue h1 loads before the barrier ----
  #pragma unroll
  for (int it = 0; it < 8; ++it) sa[it] = *(const uint4*)(AsrcB + HSA + (it*256 + tid)*16);
  #pragma unroll
  for (int it = 0; it < 4; ++it) sb[it] = *(const uint4*)(BsrcB + HSA + (it*256 + tid)*16);
  __syncthreads();

  // ---- stage B ----
  f32x16 acc[2][4];
  #pragma unroll
  for (int mb = 0; mb < 2; ++mb)
    #pragma unroll
    for (int nb = 0; nb < 4; ++nb)
      #pragma unroll
      for (int r = 0; r < 16; ++r) acc[mb][nb][r] = 0.f;

  #pragma unroll
  for (int ks = 0; ks < 4; ++ks){                 // h0
    const int kb = ks*32 + hi*16;
    bf16x8 aF[2], bF[4];
    #pragma unroll
    for (int mb = 0; mb < 2; ++mb){
      int m = wr*64 + mb*32 + ln;
      aF[mb] = lds_frag(shA, (m >> 1)*256 + ((((m & 1)*128 + kb)) ^ (((m >> 1) & 15) << 4)));
    }
    #pragma unroll
    for (int nb = 0; nb < 4; ++nb){
      int nB = nb*32 + ln;
      bF[nb] = lds_frag(shB, (nB >> 1)*256 + ((((nB & 1)*128 + kb)) ^ (((nB >> 1) & 15) << 4)));
    }
    #pragma unroll
    for (int mb = 0; mb < 2; ++mb)
      #pragma unroll
      for (int nb = 0; nb < 4; ++nb)
        acc[mb][nb] = __builtin_amdgcn_mfma_f32_32x32x16_bf16(aF[mb], bF[nb], acc[mb][nb], 0, 0, 0);
  }
  __syncthreads();          // h0 reads done

  // ---- write h1 ----
  #pragma unroll
  for (int it = 0; it < 8; ++it) *(uint4*)(shA + (it*256 + tid)*16) = sa[it];
  #pragma unroll
  for (int it = 0; it < 4; ++it) *(uint4*)(shB + (it*256 + tid)*16) = sb[it];
  __syncthreads();

  #pragma unroll
  for (int ks = 0; ks < 4; ++ks){                 // h1
    const int kb = ks*32 + hi*16;
    bf16x8 aF[2], bF[4];
    #pragma unroll
    for (int mb = 0; mb < 2; ++mb){
      int m = wr*64 + mb*32 + ln;
      aF[mb] = lds_frag(shA, (m >> 1)*256 + ((((m & 1)*128 + kb)) ^ (((m >> 1) & 15) << 4)));
    }
    #pragma unroll
    for (int nb = 0; nb < 4; ++nb){
      int nB = nb*32 + ln;
      bF[nb] = lds_frag(shB, (nB >> 1)*256 + ((((nB & 1)*128 + kb)) ^ (((nB >> 1) & 15) << 4)));
    }
    #pragma unroll
    for (int mb = 0; mb < 2; ++mb)
      #pragma unroll
      for (int nb = 0; nb < 4; ++nb)
        acc[mb][nb] = __builtin_amdgcn_mfma_f32_32x32x16_bf16(aF[mb], bF[nb], acc[mb][nb], 0, 0, 0);
  }

  // ---- Wt prefetch rounds 0-1 (lands during P-write) ----
  const int kh = w >> 1, zh = w & 1;
  const char* wb0 = (const char*)Wt + (size_t)(zh*64      + ln)*2048 + kh*1024 + hi*64;
  const char* wb1 = (const char*)Wt + (size_t)(zh*64 + 32 + ln)*2048 + kh*1024 + hi*64;
  uint4 wr0[8], wr1[8];
  #pragma unroll
  for (int u = 0; u < 8; ++u){
    int off = (u >> 2)*128 + (u & 3)*16;
    wr0[u] = *(const uint4*)(wb0 + off);
    wr1[u] = *(const uint4*)(wb1 + off);
  }
  __syncthreads();          // h1 reads done; P may overwrite

  // ---- write P (pos layout): pair p = (wr*2+mb)*4 + nb ----
  #pragma unroll
  for (int mb = 0; mb < 2; ++mb)
    #pragma unroll
    for (int nb = 0; nb < 4; ++nb){
      int p = (wr*2 + mb)*4 + nb;
      int base = p*2048, sw = (p & 15) << 4;
      #pragma unroll
      for (int g = 0; g < 4; ++g){
        u32 lo   = (u32)bf16bits(acc[mb][nb][4*g + 0]) | ((u32)bf16bits(acc[mb][nb][4*g + 1]) << 16);
        u32 hi32 = (u32)bf16bits(acc[mb][nb][4*g + 2]) | ((u32)bf16bits(acc[mb][nb][4*g + 3]) << 16);
        uint2 v; v.x = lo; v.y = hi32;
        int off = ((2*g + hi)*256 + ln*8) ^ sw;
        *(uint2*)(shP + base + off) = v;
      }
    }
  __syncthreads();

  // ---- stage C: z[p][z'] partials, K-half kh, z-half zh; 8 rounds of 4 k-steps ----
  f32x16 zc0, zc1;
  #pragma unroll
  for (int r = 0; r < 16; ++r){ zc0[r] = 0.f; zc1[r] = 0.f; }

  const char* prow = shP + (size_t)ln*2048;
  const int sw2 = (ln & 15) << 4;
  const int kbase = kh*1024;

  #pragma unroll
  for (int rd = 0; rd < 8; ++rd){
    #pragma unroll
    for (int u = 0; u < 4; ++u){
      int ks2 = rd*4 + u;
      bf16x8 aF = lds_frag(prow, (kbase + ks2*32 + hi*16) ^ sw2);
      union { uint4 q; bf16x8 v; } b0, b1;
      b0.q = wr0[(rd & 1)*4 + u];
      b1.q = wr1[(rd & 1)*4 + u];
      zc0 = __builtin_amdgcn_mfma_f32_32x32x16_bf16(aF, b0.v, zc0, 0, 0, 0);
      zc1 = __builtin_amdgcn_mfma_f32_32x32x16_bf16(aF, b1.v, zc1, 0, 0, 0);
      if (rd < 6){
        int off = (rd + 2)*128 + u*16;
        wr0[(rd & 1)*4 + u] = *(const uint4*)(wb0 + off);
        wr1[(rd & 1)*4 + u] = *(const uint4*)(wb1 + off);
      }
    }
  }
  __syncthreads();          // P reads done

  // ---- cross-kh reduce through P space; epilogue by kh=0 waves ----
  float* red = (float*)sh.P;   // [32 p][128 z] f32 = 16KB
  if (kh == 1){
    #pragma unroll
    for (int r = 0; r < 16; ++r){
      int p = (r & 3) + ((r >> 2) << 3) + (hi << 2);
      red[p*128 + zh*64      + ln] = zc0[r];
      red[p*128 + zh*64 + 32 + ln] = zc1[r];
    }
  }
  __syncthreads();
  if (kh == 0){
    #pragma unroll
    for (int r = 0; r < 16; ++r){
      int p = (r & 3) + ((r >> 2) << 3) + (hi << 2);
      int i = bi*8 + (p >> 2), j = bj*4 + (p & 3);
      float inv = 1.0f / (nrm[p] + 0.001f);
      {
        int z = zh*64 + ln;
        float v = (zc0[r] + red[p*128 + z] + b_out[z]) * inv;
        out[((size_t)i*N_PTS + j)*CZ + z] = v;
      }
      {
        int z = zh*64 + 32 + ln;
        float v = (zc1[r] + red[p*128 + z] + b_out[z]) * inv;
        out[((size_t)i*N_PTS + j)*CZ + z] = v;
      }
    }
  }
}

extern "C" void kernel_launch(void* const* d_in, const int* in_sizes, int n_in,
                              void* d_out, int out_size, void* d_ws, size_t ws_size,
                              hipStream_t stream) {
  (void)in_sizes; (void)n_in; (void)out_size; (void)ws_size;
  const float* msa   = (const float*)d_in[0];
  const float* mask  = (const float*)d_in[1];
  const float* gamma = (const float*)d_in[2];
  const float* beta  = (const float*)d_in[3];
  const float* wa    = (const float*)d_in[4];
  const float* wb    = (const float*)d_in[5];
  const float* wout  = (const float*)d_in[6];
  const float* bout  = (const float*)d_in[7];

  __hip_bfloat16* A_ws = (__hip_bfloat16*)d_ws;              // [2][6144][256B] bf16
  __hip_bfloat16* B_ws = A_ws + (size_t)NC*S_DIM;            // [2][6144][256B] bf16
  __hip_bfloat16* Wt   = B_ws + (size_t)NC*S_DIM;            // [128][1024] bf16 (pos-permuted)
  float* nrm_g = (float*)(Wt + (size_t)CZ*1024);             // [384][384] f32
  float* outp  = (float*)d_out;                              // [384][384][128] f32

  k_wt<<<512, 256, 0, stream>>>(wout, Wt);
  k_norm<<<N_PTS, 384, 0, stream>>>(mask, nrm_g);
  k_lnproj<<<N_PTS, 512, 0, stream>>>(msa, mask, gamma, beta, wa, wb, A_ws, B_ws);
  dim3 g2(48, 96, 1);
  k_fused<<<g2, 256, 0, stream>>>(A_ws, B_ws, Wt, bout, nrm_g, outp);
}

// Round 9
// 202.507 us; speedup vs baseline: 1.4045x; 1.4045x over previous
//
#include <hip/hip_runtime.h>
#include <hip/hip_bf16.h>

#define S_DIM 128
#define N_PTS 384
#define CM    64
#define C_DIM 32
#define CZ    128
#define NC    (N_PTS*C_DIM)   // 12288

typedef __attribute__((ext_vector_type(8)))  __bf16 bf16x8;
typedef __attribute__((ext_vector_type(16))) float  f32x16;
typedef unsigned short u16;
typedef unsigned int   u32;

__device__ __forceinline__ bf16x8 lds_frag(const void* base, int byteoff){
  union { uint4 u; bf16x8 v; } x;
  x.u = *(const uint4*)((const char*)base + byteoff);
  return x.v;
}
// native pair pack -> compiler emits v_cvt_pk_bf16_f32 (RNE), replaces 10-op manual path
__device__ __forceinline__ u32 pk2(float a, float b){
  __hip_bfloat162 h;
  h.x = (__hip_bfloat16)a;
  h.y = (__hip_bfloat16)b;
  union { __hip_bfloat162 h2; u32 u; } c; c.h2 = h;
  return c.u;
}

// ---------------- kernel 0: W [1024,128] (f32) -> Wt_perm [128 z][1024 mem-idx] (bf16) ------
// mem idx mi: e=mi&7, j=(mi>>3)&3, hi=(mi>>5)&1, Q=mi>>6 ; ks=Q*4+j ; pos=ks*16+hi*8+e
// pos -> original k: c = ((pos>>7)<<2)|(pos&3), d = (pos>>2)&31, k = c*32+d
__global__ __launch_bounds__(256) void k_wt(const float* __restrict__ w_out,
                                            __hip_bfloat16* __restrict__ wt){
  int o = blockIdx.x*256 + threadIdx.x;     // 131072 total
  int z = o >> 10, mi = o & 1023;
  int e = mi & 7, j = (mi >> 3) & 3, hi = (mi >> 5) & 1, Q = mi >> 6;
  int ks = Q*4 + j;
  int pos = ks*16 + hi*8 + e;
  int c = ((pos >> 7) << 2) | (pos & 3);
  int d = (pos >> 2) & 31;
  int k = c*32 + d;
  wt[o] = (__hip_bfloat16)w_out[k*CZ + z];
}

// ---------------- kernel 0b: norm[i][j] = sum_s mask[s,i]*mask[s,j] ----------------
__global__ __launch_bounds__(384) void k_norm(const float* __restrict__ mask,
                                              float* __restrict__ nrm_g){
  int i = blockIdx.x, j = threadIdx.x;
  float a = 0.f;
  #pragma unroll 8
  for (int s = 0; s < S_DIM; ++s)
    a += mask[s*N_PTS + i] * mask[s*N_PTS + j];
  nrm_g[i*N_PTS + j] = a;
}

// ---------------- kernel 1: LN + projections via MFMA, coalesced transposed outputs --------
__global__ __launch_bounds__(512) void k_lnproj(
    const float* __restrict__ msa, const float* __restrict__ mask,
    const float* __restrict__ gamma, const float* __restrict__ beta,
    const float* __restrict__ wa, const float* __restrict__ wb,
    __hip_bfloat16* __restrict__ A_ws, __hip_bfloat16* __restrict__ B_ws){
  __shared__ union {
    u16   X[128*64];     // 16KB bf16 LN'd [s][m]
    float T[64*128];     // 32KB f32 [col][s]
  } sh;
  __shared__ float ln_mk[128];

  const int tid = threadIdx.x, w = tid >> 6, l = tid & 63;
  const int hi = l >> 5, ln = l & 31;
  const int n = blockIdx.x;

  if (tid < 128) ln_mk[tid] = mask[tid*N_PTS + n];

  const float g  = gamma[l];
  const float be = beta[l];

  #pragma unroll
  for (int t = 0; t < 16; ++t){
    int s = w*16 + t;
    float x = msa[((size_t)s*N_PTS + n)*CM + l];
    float sum = x;
    #pragma unroll
    for (int m = 1; m < 64; m <<= 1) sum += __shfl_xor(sum, m, 64);
    float mu = sum * (1.0f/64.0f);
    float dx = x - mu;
    float vs = dx*dx;
    #pragma unroll
    for (int m = 1; m < 64; m <<= 1) vs += __shfl_xor(vs, m, 64);
    float rstd = rsqrtf(vs*(1.0f/64.0f) + 1e-5f);
    float xn = dx*rstd*g + be;
    __hip_bfloat16 hx = (__hip_bfloat16)xn;
    *(u16*)((char*)sh.X + s*128 + ((l*2) ^ ((s&7)<<4))) = *(u16*)&hx;
  }
  __syncthreads();

  const int mb = w >> 1, mat = w & 1;
  const float* W = mat ? wb : wa;
  f32x16 pacc;
  #pragma unroll
  for (int r = 0; r < 16; ++r) pacc[r] = 0.f;
  #pragma unroll
  for (int ks = 0; ks < 4; ++ks){
    int srow = mb*32 + ln;
    bf16x8 aF = lds_frag(sh.X, srow*128 + (((ks*32 + hi*16)) ^ ((srow&7)<<4)));
    union { u32 u[4]; bf16x8 v; } bx;
    #pragma unroll
    for (int e = 0; e < 4; ++e){
      int m = ks*16 + hi*8 + e*2;
      bx.u[e] = pk2(W[m*C_DIM + ln], W[(m+1)*C_DIM + ln]);
    }
    pacc = __builtin_amdgcn_mfma_f32_32x32x16_bf16(aF, bx.v, pacc, 0, 0, 0);
  }
  __syncthreads();

  const int col = mat*32 + ln;
  #pragma unroll
  for (int r = 0; r < 16; ++r){
    int rr = (r & 3) + ((r >> 2) << 3) + (hi << 2);
    int s = mb*32 + rr;
    *(float*)((char*)sh.T + col*512 + ((s*4) ^ ((col&7)<<4))) = pacc[r] * ln_mk[s];
  }
  __syncthreads();

  {
    int col2 = tid >> 3, sc = tid & 7;
    __hip_bfloat16* O = (col2 < 32) ? A_ws : B_ws;
    int row = n*C_DIM + (col2 & 31);
    uint4 pk_0, pk_1;
    u32* pw0 = (u32*)&pk_0;
    u32* pw1 = (u32*)&pk_1;
    #pragma unroll
    for (int q = 0; q < 4; ++q){
      union { uint4 u4; float f[4]; } rd;
      rd.u4 = *(const uint4*)((const char*)sh.T + col2*512 + ((sc*64 + q*16) ^ ((col2&7)<<4)));
      u32 a = pk2(rd.f[0], rd.f[1]);
      u32 b = pk2(rd.f[2], rd.f[3]);
      if (q < 2){ pw0[q*2] = a; pw0[q*2+1] = b; }
      else      { pw1[(q-2)*2] = a; pw1[(q-2)*2+1] = b; }
    }
    *(uint4*)((char*)O + (size_t)row*256 + sc*32)      = pk_0;
    *(uint4*)((char*)O + (size_t)row*256 + sc*32 + 16) = pk_1;
  }
}

// ---------------- kernel 2: fused, 8x8 tile ----------------
// grid (48,48), 512 threads (8 waves).
// Stage B: waves (wr,wc) 2x4, 256x256 over K=128 (R7, conflict-free).
// Stage C: waves (ph = p-half, zq = z-quarter); each wave owns 32p x 32z, FULL K=1024.
//          No cross-wave reduce; 3 barriers total; all-wave epilogue.
__global__ __launch_bounds__(512, 2) void k_fused(
    const __hip_bfloat16* __restrict__ A_ws, const __hip_bfloat16* __restrict__ B_ws,
    const __hip_bfloat16* __restrict__ Wt,  const float* __restrict__ b_out,
    const float* __restrict__ nrm_g, float* __restrict__ out){
  __shared__ union {
    struct { u16 A[256*128]; u16 B[256*128]; } s1;   // 64KB + 64KB slabs (256B rows)
    struct { u16 P[64*1024]; } s2;                   // 128KB P (pos layout, swizzled)
  } sh;
  __shared__ float nrm[64];

  const int tid = threadIdx.x;
  const int w = tid >> 6, l = tid & 63;
  const int hi = l >> 5, ln = l & 31;
  const int bi = blockIdx.x, bj = blockIdx.y;

  // ---- staging loads (issue first) ----
  const char* Asrc = (const char*)(A_ws + (size_t)bi*256*S_DIM);
  const char* Bsrc = (const char*)(B_ws + (size_t)bj*256*S_DIM);
  u16* shA = sh.s1.A;
  u16* shB = sh.s1.B;
  #pragma unroll
  for (int it = 0; it < 8; ++it){
    int o = (it*512 + tid) * 16;
    int row = o >> 8, kb = o & 255;
    int dst = row*256 + (kb ^ ((row & 15) << 4));
    *(uint4*)((char*)shA + dst) = *(const uint4*)(Asrc + o);
    *(uint4*)((char*)shB + dst) = *(const uint4*)(Bsrc + o);
  }

  // ---- early stage-C prefetch: nrm + first 8 k-steps of this wave's Wt rows ----
  if (tid < 64){
    int i = bi*8 + (tid >> 3), jj = bj*8 + (tid & 7);
    nrm[tid] = nrm_g[i*N_PTS + jj];
  }
  const int ph = w >> 2, zq = w & 3;      // stage-C role: p-half, z-quarter
  const char* wbase = (const char*)Wt + (size_t)(zq*32 + ln)*2048 + hi*64;
  uint4 wreg[8];
  #pragma unroll
  for (int u = 0; u < 8; ++u)
    wreg[u] = *(const uint4*)(wbase + (u>>2)*128 + (u&3)*16);
  __syncthreads();

  // ---- stage B (R7 verbatim) ----
  const int wr = w >> 2, wc = w & 3;
  f32x16 acc[4][2];
  #pragma unroll
  for (int mb = 0; mb < 4; ++mb)
    #pragma unroll
    for (int nb = 0; nb < 2; ++nb)
      #pragma unroll
      for (int r = 0; r < 16; ++r) acc[mb][nb][r] = 0.f;

  #pragma unroll
  for (int ks = 0; ks < 8; ++ks){
    const int k0b = ks*32 + hi*16;
    bf16x8 aF[4], bF[2];
    #pragma unroll
    for (int mb = 0; mb < 4; ++mb){
      int m = wr*128 + mb*32 + ln;
      aF[mb] = lds_frag(shA, m*256 + (k0b ^ ((m & 15) << 4)));
    }
    #pragma unroll
    for (int nb = 0; nb < 2; ++nb){
      int n = wc*64 + nb*32 + ln;
      bF[nb] = lds_frag(shB, n*256 + (k0b ^ ((n & 15) << 4)));
    }
    #pragma unroll
    for (int mb = 0; mb < 4; ++mb)
      #pragma unroll
      for (int nb = 0; nb < 2; ++nb)
        acc[mb][nb] = __builtin_amdgcn_mfma_f32_32x32x16_bf16(aF[mb], bF[nb], acc[mb][nb], 0, 0, 0);
  }
  __syncthreads();

  // ---- write P (pos layout, cvt_pk packed) ----
  char* shP = (char*)sh.s2.P;
  #pragma unroll
  for (int mb = 0; mb < 4; ++mb)
    #pragma unroll
    for (int nb = 0; nb < 2; ++nb){
      int p = (wr*4 + mb)*8 + (wc*2 + nb);
      int base = p*2048, sw = (p & 15) << 4;
      #pragma unroll
      for (int g = 0; g < 4; ++g){
        uint2 v;
        v.x = pk2(acc[mb][nb][4*g + 0], acc[mb][nb][4*g + 1]);
        v.y = pk2(acc[mb][nb][4*g + 2], acc[mb][nb][4*g + 3]);
        int off = ((2*g + hi)*256 + ln*8) ^ sw;
        *(uint2*)(shP + base + off) = v;
      }
    }
  __syncthreads();

  // ---- stage C: z[p][z'] = P[p,:] . Wt[z',:], full K=1024 per wave ----
  f32x16 zca, zcb;
  #pragma unroll
  for (int r = 0; r < 16; ++r){ zca[r] = 0.f; zcb[r] = 0.f; }

  const char* prow = shP + (size_t)(ph*32 + ln)*2048;
  const int sw2 = (ln & 15) << 4;

  #pragma unroll
  for (int rd = 0; rd < 16; ++rd){
    bf16x8 a[4];
    #pragma unroll
    for (int u = 0; u < 4; ++u)
      a[u] = lds_frag(prow, ((rd*4 + u)*32 + hi*16) ^ sw2);
    #pragma unroll
    for (int u = 0; u < 4; ++u){
      union { uint4 q; bf16x8 v; } bx; bx.q = wreg[(rd & 1)*4 + u];
      if (u & 1) zcb = __builtin_amdgcn_mfma_f32_32x32x16_bf16(a[u], bx.v, zcb, 0, 0, 0);
      else       zca = __builtin_amdgcn_mfma_f32_32x32x16_bf16(a[u], bx.v, zca, 0, 0, 0);
      if (rd < 14)
        wreg[(rd & 1)*4 + u] = *(const uint4*)(wbase + (rd + 2)*128 + u*16);
    }
  }
  #pragma unroll
  for (int r = 0; r < 16; ++r) zca[r] += zcb[r];

  // ---- epilogue: every wave stores its own 32p x 32z block ----
  const int z = zq*32 + ln;
  const float bo = b_out[z];
  #pragma unroll
  for (int r = 0; r < 16; ++r){
    int p = ph*32 + (r & 3) + ((r >> 2) << 3) + (hi << 2);
    int i = bi*8 + (p >> 3), j = bj*8 + (p & 7);
    float val = (zca[r] + bo) / (nrm[p] + 0.001f);
    out[((size_t)i*N_PTS + j)*CZ + z] = val;
  }
}

extern "C" void kernel_launch(void* const* d_in, const int* in_sizes, int n_in,
                              void* d_out, int out_size, void* d_ws, size_t ws_size,
                              hipStream_t stream) {
  (void)in_sizes; (void)n_in; (void)out_size; (void)ws_size;
  const float* msa   = (const float*)d_in[0];
  const float* mask  = (const float*)d_in[1];
  const float* gamma = (const float*)d_in[2];
  const float* beta  = (const float*)d_in[3];
  const float* wa    = (const float*)d_in[4];
  const float* wb    = (const float*)d_in[5];
  const float* wout  = (const float*)d_in[6];
  const float* bout  = (const float*)d_in[7];

  __hip_bfloat16* A_ws = (__hip_bfloat16*)d_ws;              // [12288][128] bf16
  __hip_bfloat16* B_ws = A_ws + (size_t)NC*S_DIM;            // [12288][128] bf16
  __hip_bfloat16* Wt   = B_ws + (size_t)NC*S_DIM;            // [128][1024] bf16 (pos-permuted)
  float* nrm_g = (float*)(Wt + (size_t)CZ*1024);             // [384][384] f32
  float* outp  = (float*)d_out;                              // [384][384][128] f32

  k_wt<<<512, 256, 0, stream>>>(wout, Wt);
  k_norm<<<N_PTS, 384, 0, stream>>>(mask, nrm_g);
  k_lnproj<<<N_PTS, 512, 0, stream>>>(msa, mask, gamma, beta, wa, wb, A_ws, B_ws);
  dim3 g2(48, 48, 1);
  k_fused<<<g2, 512, 0, stream>>>(A_ws, B_ws, Wt, bout, nrm_g, outp);
}

// Round 10
// 155.490 us; speedup vs baseline: 1.8292x; 1.3024x over previous
//
#include <hip/hip_runtime.h>
#include <hip/hip_bf16.h>

#define S_DIM 128
#define N_PTS 384
#define CM    64
#define C_DIM 32
#define CZ    128
#define NC    (N_PTS*C_DIM)   // 12288

typedef __attribute__((ext_vector_type(8)))  __bf16 bf16x8;
typedef __attribute__((ext_vector_type(16))) float  f32x16;
typedef unsigned short u16;
typedef unsigned int   u32;

__device__ __forceinline__ bf16x8 lds_frag(const void* base, int byteoff){
  union { uint4 u; bf16x8 v; } x;
  x.u = *(const uint4*)((const char*)base + byteoff);
  return x.v;
}
// native pair pack -> v_cvt_pk_bf16_f32
__device__ __forceinline__ u32 pk2(float a, float b){
  __hip_bfloat162 h;
  h.x = (__hip_bfloat16)a;
  h.y = (__hip_bfloat16)b;
  union { __hip_bfloat162 h2; u32 u; } c; c.h2 = h;
  return c.u;
}

// ---------------- kernel 0: W [1024,128] (f32) -> Wt_perm [128 z][1024 mem-idx] (bf16) ------
// mem idx mi: e=mi&7, j=(mi>>3)&3, hi=(mi>>5)&1, Q=mi>>6 ; ks=Q*4+j ; pos=ks*16+hi*8+e
// pos -> original k: c = ((pos>>7)<<2)|(pos&3), d = (pos>>2)&31, k = c*32+d
__global__ __launch_bounds__(256) void k_wt(const float* __restrict__ w_out,
                                            __hip_bfloat16* __restrict__ wt){
  int o = blockIdx.x*256 + threadIdx.x;     // 131072 total
  int z = o >> 10, mi = o & 1023;
  int e = mi & 7, j = (mi >> 3) & 3, hi = (mi >> 5) & 1, Q = mi >> 6;
  int ks = Q*4 + j;
  int pos = ks*16 + hi*8 + e;
  int c = ((pos >> 7) << 2) | (pos & 3);
  int d = (pos >> 2) & 31;
  int k = c*32 + d;
  wt[o] = (__hip_bfloat16)w_out[k*CZ + z];
}

// ---------------- kernel 0b: norm[i][j] = sum_s mask[s,i]*mask[s,j] ----------------
__global__ __launch_bounds__(384) void k_norm(const float* __restrict__ mask,
                                              float* __restrict__ nrm_g){
  int i = blockIdx.x, j = threadIdx.x;
  float a = 0.f;
  #pragma unroll 8
  for (int s = 0; s < S_DIM; ++s)
    a += mask[s*N_PTS + i] * mask[s*N_PTS + j];
  nrm_g[i*N_PTS + j] = a;
}

// ---------------- kernel 1: LN + projections via MFMA, coalesced transposed outputs --------
__global__ __launch_bounds__(512) void k_lnproj(
    const float* __restrict__ msa, const float* __restrict__ mask,
    const float* __restrict__ gamma, const float* __restrict__ beta,
    const float* __restrict__ wa, const float* __restrict__ wb,
    __hip_bfloat16* __restrict__ A_ws, __hip_bfloat16* __restrict__ B_ws){
  __shared__ union {
    u16   X[128*64];     // 16KB bf16 LN'd [s][m]
    float T[64*128];     // 32KB f32 [col][s]
  } sh;
  __shared__ float ln_mk[128];

  const int tid = threadIdx.x, w = tid >> 6, l = tid & 63;
  const int hi = l >> 5, ln = l & 31;
  const int n = blockIdx.x;

  if (tid < 128) ln_mk[tid] = mask[tid*N_PTS + n];

  const float g  = gamma[l];
  const float be = beta[l];

  #pragma unroll
  for (int t = 0; t < 16; ++t){
    int s = w*16 + t;
    float x = msa[((size_t)s*N_PTS + n)*CM + l];
    float sum = x;
    #pragma unroll
    for (int m = 1; m < 64; m <<= 1) sum += __shfl_xor(sum, m, 64);
    float mu = sum * (1.0f/64.0f);
    float dx = x - mu;
    float vs = dx*dx;
    #pragma unroll
    for (int m = 1; m < 64; m <<= 1) vs += __shfl_xor(vs, m, 64);
    float rstd = rsqrtf(vs*(1.0f/64.0f) + 1e-5f);
    float xn = dx*rstd*g + be;
    __hip_bfloat16 hx = (__hip_bfloat16)xn;
    *(u16*)((char*)sh.X + s*128 + ((l*2) ^ ((s&7)<<4))) = *(u16*)&hx;
  }
  __syncthreads();

  const int mb = w >> 1, mat = w & 1;
  const float* W = mat ? wb : wa;
  f32x16 pacc;
  #pragma unroll
  for (int r = 0; r < 16; ++r) pacc[r] = 0.f;
  #pragma unroll
  for (int ks = 0; ks < 4; ++ks){
    int srow = mb*32 + ln;
    bf16x8 aF = lds_frag(sh.X, srow*128 + (((ks*32 + hi*16)) ^ ((srow&7)<<4)));
    union { u32 u[4]; bf16x8 v; } bx;
    #pragma unroll
    for (int e = 0; e < 4; ++e){
      int m = ks*16 + hi*8 + e*2;
      bx.u[e] = pk2(W[m*C_DIM + ln], W[(m+1)*C_DIM + ln]);
    }
    pacc = __builtin_amdgcn_mfma_f32_32x32x16_bf16(aF, bx.v, pacc, 0, 0, 0);
  }
  __syncthreads();

  const int col = mat*32 + ln;
  #pragma unroll
  for (int r = 0; r < 16; ++r){
    int rr = (r & 3) + ((r >> 2) << 3) + (hi << 2);
    int s = mb*32 + rr;
    *(float*)((char*)sh.T + col*512 + ((s*4) ^ ((col&7)<<4))) = pacc[r] * ln_mk[s];
  }
  __syncthreads();

  {
    int col2 = tid >> 3, sc = tid & 7;
    __hip_bfloat16* O = (col2 < 32) ? A_ws : B_ws;
    int row = n*C_DIM + (col2 & 31);
    uint4 pk_0, pk_1;
    u32* pw0 = (u32*)&pk_0;
    u32* pw1 = (u32*)&pk_1;
    #pragma unroll
    for (int q = 0; q < 4; ++q){
      union { uint4 u4; float f[4]; } rd;
      rd.u4 = *(const uint4*)((const char*)sh.T + col2*512 + ((sc*64 + q*16) ^ ((col2&7)<<4)));
      u32 a = pk2(rd.f[0], rd.f[1]);
      u32 b = pk2(rd.f[2], rd.f[3]);
      if (q < 2){ pw0[q*2] = a; pw0[q*2+1] = b; }
      else      { pw1[(q-2)*2] = a; pw1[(q-2)*2+1] = b; }
    }
    *(uint4*)((char*)O + (size_t)row*256 + sc*32)      = pk_0;
    *(uint4*)((char*)O + (size_t)row*256 + sc*32 + 16) = pk_1;
  }
}

// ---------------- kernel 2: fused, 8x8 tile (R7 structure + pk2 + setprio + 3-bank wreg) ----
// grid (48,48), 512 threads (8 waves).
// Stage B: waves (wr,wc) 2x4, 256x256 over K=128.
// Stage C: waves (kh = K-half, cc = z-quarter); M=64 (zc0/zc1); Wt read once per block;
//          wreg[12] 3-bank rotation, refills hoisted to round start; LDS kh-reduce.
__global__ __launch_bounds__(512, 2) void k_fused(
    const __hip_bfloat16* __restrict__ A_ws, const __hip_bfloat16* __restrict__ B_ws,
    const __hip_bfloat16* __restrict__ Wt,  const float* __restrict__ b_out,
    const float* __restrict__ nrm_g, float* __restrict__ out){
  __shared__ union {
    struct { u16 A[256*128]; u16 B[256*128]; } s1;   // 64KB + 64KB slabs (256B rows)
    struct { u16 P[64*1024]; } s2;                   // 128KB P (pos layout, swizzled)
  } sh;
  __shared__ float nrm[64];

  const int tid = threadIdx.x;
  const int w = tid >> 6, l = tid & 63;
  const int hi = l >> 5, ln = l & 31;
  const int bi = blockIdx.x, bj = blockIdx.y;

  // ---- staging loads (issue first) ----
  const char* Asrc = (const char*)(A_ws + (size_t)bi*256*S_DIM);
  const char* Bsrc = (const char*)(B_ws + (size_t)bj*256*S_DIM);
  u16* shA = sh.s1.A;
  u16* shB = sh.s1.B;
  #pragma unroll
  for (int it = 0; it < 8; ++it){
    int o = (it*512 + tid) * 16;
    int row = o >> 8, kb = o & 255;
    int dst = row*256 + (kb ^ ((row & 15) << 4));
    *(uint4*)((char*)shA + dst) = *(const uint4*)(Asrc + o);
    *(uint4*)((char*)shB + dst) = *(const uint4*)(Bsrc + o);
  }

  // ---- early stage-C prefetch: nrm + wreg banks 0,1 (rounds 0,1) ----
  if (tid < 64){
    int i = bi*8 + (tid >> 3), jj = bj*8 + (tid & 7);
    nrm[tid] = nrm_g[i*N_PTS + jj];
  }
  const int kh = w >> 2, cc = w & 3;      // stage-C role
  const char* wbase = (const char*)Wt + (size_t)(cc*32 + ln)*2048 + kh*1024 + hi*64;
  uint4 wreg[12];
  #pragma unroll
  for (int u = 0; u < 8; ++u)
    wreg[u] = *(const uint4*)(wbase + (u>>2)*128 + (u&3)*16);
  __syncthreads();

  // ---- stage B ----
  const int wr = w >> 2, wc = w & 3;
  f32x16 acc[4][2];
  #pragma unroll
  for (int mb = 0; mb < 4; ++mb)
    #pragma unroll
    for (int nb = 0; nb < 2; ++nb)
      #pragma unroll
      for (int r = 0; r < 16; ++r) acc[mb][nb][r] = 0.f;

  #pragma unroll
  for (int ks = 0; ks < 8; ++ks){
    const int k0b = ks*32 + hi*16;
    bf16x8 aF[4], bF[2];
    #pragma unroll
    for (int mb = 0; mb < 4; ++mb){
      int m = wr*128 + mb*32 + ln;
      aF[mb] = lds_frag(shA, m*256 + (k0b ^ ((m & 15) << 4)));
    }
    #pragma unroll
    for (int nb = 0; nb < 2; ++nb){
      int n = wc*64 + nb*32 + ln;
      bF[nb] = lds_frag(shB, n*256 + (k0b ^ ((n & 15) << 4)));
    }
    __builtin_amdgcn_s_setprio(1);
    #pragma unroll
    for (int mb = 0; mb < 4; ++mb)
      #pragma unroll
      for (int nb = 0; nb < 2; ++nb)
        acc[mb][nb] = __builtin_amdgcn_mfma_f32_32x32x16_bf16(aF[mb], bF[nb], acc[mb][nb], 0, 0, 0);
    __builtin_amdgcn_s_setprio(0);
  }
  __syncthreads();

  // ---- write P (pos layout, cvt_pk packed) ----
  char* shP = (char*)sh.s2.P;
  #pragma unroll
  for (int mb = 0; mb < 4; ++mb)
    #pragma unroll
    for (int nb = 0; nb < 2; ++nb){
      int p = (wr*4 + mb)*8 + (wc*2 + nb);
      int base = p*2048, sw = (p & 15) << 4;
      #pragma unroll
      for (int g = 0; g < 4; ++g){
        uint2 v;
        v.x = pk2(acc[mb][nb][4*g + 0], acc[mb][nb][4*g + 1]);
        v.y = pk2(acc[mb][nb][4*g + 2], acc[mb][nb][4*g + 3]);
        int off = ((2*g + hi)*256 + ln*8) ^ sw;
        *(uint2*)(shP + base + off) = v;
      }
    }
  __syncthreads();

  // ---- stage C: z[p][z'] partials over K-half kh; M=64 (zc0: p=ln, zc1: p=32+ln) ----
  f32x16 zc0, zc1;
  #pragma unroll
  for (int r = 0; r < 16; ++r){ zc0[r] = 0.f; zc1[r] = 0.f; }

  const char* prow0 = shP + (size_t)ln*2048;
  const char* prow1 = shP + (size_t)(32 + ln)*2048;
  const int sw2 = (ln & 15) << 4;
  const int kbase = kh*1024;     // byte base of K-half in pos space

  #pragma unroll
  for (int rd = 0; rd < 8; ++rd){
    // refills for round rd+2 -> bank (rd+2)%3 (not consumed in rd or rd+1)
    if (rd < 6){
      #pragma unroll
      for (int u = 0; u < 4; ++u)
        wreg[((rd + 2) % 3)*4 + u] = *(const uint4*)(wbase + (rd + 2)*128 + u*16);
    }
    bf16x8 a0[4], a1[4];
    #pragma unroll
    for (int u = 0; u < 4; ++u){
      int off = (kbase + (rd*4 + u)*32 + hi*16) ^ sw2;
      a0[u] = lds_frag(prow0, off);
      a1[u] = lds_frag(prow1, off);
    }
    __builtin_amdgcn_s_setprio(1);
    #pragma unroll
    for (int u = 0; u < 4; ++u){
      union { uint4 q; bf16x8 v; } bx; bx.q = wreg[(rd % 3)*4 + u];
      zc0 = __builtin_amdgcn_mfma_f32_32x32x16_bf16(a0[u], bx.v, zc0, 0, 0, 0);
      zc1 = __builtin_amdgcn_mfma_f32_32x32x16_bf16(a1[u], bx.v, zc1, 0, 0, 0);
    }
    __builtin_amdgcn_s_setprio(0);
  }
  __syncthreads();   // all P reads complete; P space free

  // ---- cross-K-half reduce through P space; epilogue by kh=0 waves ----
  float* red = (float*)sh.s2.P;   // [64 p][128 z] f32 = 32KB
  if (kh == 1){
    #pragma unroll
    for (int r = 0; r < 16; ++r){
      int pr = (r & 3) + ((r >> 2) << 3) + (hi << 2);
      red[pr*128 + cc*32 + ln]        = zc0[r];
      red[(32 + pr)*128 + cc*32 + ln] = zc1[r];
    }
  }
  __syncthreads();
  if (kh == 0){
    const int z = cc*32 + ln;
    const float bo = b_out[z];
    #pragma unroll
    for (int r = 0; r < 16; ++r){
      int pr = (r & 3) + ((r >> 2) << 3) + (hi << 2);
      {
        int p = pr;
        float v = (zc0[r] + red[p*128 + z] + bo) / (nrm[p] + 0.001f);
        int i = bi*8 + (p >> 3), j = bj*8 + (p & 7);
        out[((size_t)i*N_PTS + j)*CZ + z] = v;
      }
      {
        int p = 32 + pr;
        float v = (zc1[r] + red[p*128 + z] + bo) / (nrm[p] + 0.001f);
        int i = bi*8 + (p >> 3), j = bj*8 + (p & 7);
        out[((size_t)i*N_PTS + j)*CZ + z] = v;
      }
    }
  }
}

extern "C" void kernel_launch(void* const* d_in, const int* in_sizes, int n_in,
                              void* d_out, int out_size, void* d_ws, size_t ws_size,
                              hipStream_t stream) {
  (void)in_sizes; (void)n_in; (void)out_size; (void)ws_size;
  const float* msa   = (const float*)d_in[0];
  const float* mask  = (const float*)d_in[1];
  const float* gamma = (const float*)d_in[2];
  const float* beta  = (const float*)d_in[3];
  const float* wa    = (const float*)d_in[4];
  const float* wb    = (const float*)d_in[5];
  const float* wout  = (const float*)d_in[6];
  const float* bout  = (const float*)d_in[7];

  __hip_bfloat16* A_ws = (__hip_bfloat16*)d_ws;              // [12288][128] bf16
  __hip_bfloat16* B_ws = A_ws + (size_t)NC*S_DIM;            // [12288][128] bf16
  __hip_bfloat16* Wt   = B_ws + (size_t)NC*S_DIM;            // [128][1024] bf16 (pos-permuted)
  float* nrm_g = (float*)(Wt + (size_t)CZ*1024);             // [384][384] f32
  float* outp  = (float*)d_out;                              // [384][384][128] f32

  k_wt<<<512, 256, 0, stream>>>(wout, Wt);
  k_norm<<<N_PTS, 384, 0, stream>>>(mask, nrm_g);
  k_lnproj<<<N_PTS, 512, 0, stream>>>(msa, mask, gamma, beta, wa, wb, A_ws, B_ws);
  dim3 g2(48, 48, 1);
  k_fused<<<g2, 512, 0, stream>>>(A_ws, B_ws, Wt, bout, nrm_g, outp);
}